// Round 5
// baseline (318.075 us; speedup 1.0000x reference)
//
#include <hip/hip_runtime.h>
#include <math.h>

typedef _Float16 f16;
typedef f16 f16x8 __attribute__((ext_vector_type(8)));
typedef float f32x4 __attribute__((ext_vector_type(4)));

#define NT    16384
#define DIM   4096
#define NEXP  128
#define TOPK  8
#define NFLAT (NT * TOPK)        // 131072
#define NBLK  (NFLAT / 256)      // 512
#define BT    32                 // tokens per block
#define BK    64                 // k per step
#define NSTEP (DIM / BK)         // 64
#define LDK   72                 // 64 + 8 halves pad (144B rows, 16B aligned)

// ---- workspace layout (bytes) ----
#define COUNTS_OFF 0
#define GBASE_OFF  512
#define SEL_OFF    1024
#define WGT_OFF    (SEL_OFF + NFLAT * 4)
#define BH_OFF     (WGT_OFF + NFLAT * 4)
#define BO_OFF     (BH_OFF + NEXP * NBLK * 4)
#define WH_OFF     (BO_OFF + NEXP * NBLK * 4)
#define WM_OFF     (WH_OFF + NEXP * DIM * 2)

// fp32 -> fp16 high + scaled residual (next ~11 mantissa bits, normal range)
__device__ __forceinline__ void split2(float v, f16& h, f16& m) {
    h = (f16)v;
    m = (f16)((v - (float)h) * 2048.0f);
}

// ============ prologue: split 64*gw into f16 wh/wm (run once, 2 MB) ============
__global__ __launch_bounds__(256)
void wsplit_kernel(const float* __restrict__ gw, f16* __restrict__ wh,
                   f16* __restrict__ wm) {
    const int i = (blockIdx.x * 256 + threadIdx.x) * 4;
    float4 v = *(const float4*)&gw[i];
    f16 h0, m0, h1, m1, h2, m2, h3, m3;
    split2(v.x * 64.f, h0, m0); split2(v.y * 64.f, h1, m1);
    split2(v.z * 64.f, h2, m2); split2(v.w * 64.f, h3, m3);
    union { f16 f[4]; uint2 u; } ph = {{h0, h1, h2, h3}}, pm = {{m0, m1, m2, m3}};
    *(uint2*)&wh[i] = ph.u;
    *(uint2*)&wm[i] = pm.u;
}

// ============ fused: scores -> top-8 -> softmax -> sel/wgt/counts ============
// Block: 256 thr (4 waves), 32 tokens x 128 experts, full K.
// X staged via LDS (fp16 split, double-buffered, ONE barrier/step);
// W fragments read directly from L2-resident wh/wm.
__global__ __launch_bounds__(256, 4)
void fused_kernel(const float* __restrict__ x, const f16* __restrict__ whg,
                  const f16* __restrict__ wmg, float* __restrict__ wgt,
                  int* __restrict__ sel, int* __restrict__ counts) {
    __shared__ __align__(16) char smem[18432];
    f16* XH = (f16*)smem;              // [2][32][LDK]
    f16* XM = (f16*)(smem + 9216);     // [2][32][LDK]
    float* S = (float*)smem;           // epilogue reuse: [32][132] = 16896 B

    const int tid  = threadIdx.x;
    const int tok0 = blockIdx.x * BT;
    const int lane = tid & 63, w = tid >> 6;     // wave w owns experts w*32..+31
    const int fr = lane & 15, hi = lane >> 4;
    const int srow = tid >> 3;                   // staging row 0..31
    const int skq  = (tid & 7) * 8;              // staging k offset (floats)

    f32x4 acc0[2][2], acc1[2][2];
#pragma unroll
    for (int i = 0; i < 2; ++i)
#pragma unroll
        for (int j = 0; j < 2; ++j) {
            acc0[i][j] = (f32x4){0.f, 0.f, 0.f, 0.f};
            acc1[i][j] = (f32x4){0.f, 0.f, 0.f, 0.f};
        }

    const size_t xrow = (size_t)(tok0 + srow) * DIM;
    float4 ra = *(const float4*)&x[xrow + skq];
    float4 rb = *(const float4*)&x[xrow + skq + 4];

    for (int st = 0; st < NSTEP; ++st) {
        const int cur = st & 1;
        // ---- split + stage regs -> LDS[cur] ----
        {
            f16 h0, m0, h1, m1, h2, m2, h3, m3, h4, m4, h5, m5, h6, m6, h7, m7;
            split2(ra.x, h0, m0); split2(ra.y, h1, m1);
            split2(ra.z, h2, m2); split2(ra.w, h3, m3);
            split2(rb.x, h4, m4); split2(rb.y, h5, m5);
            split2(rb.z, h6, m6); split2(rb.w, h7, m7);
            union { f16 f[8]; f16x8 v; } ph = {{h0, h1, h2, h3, h4, h5, h6, h7}},
                                         pm = {{m0, m1, m2, m3, m4, m5, m6, m7}};
            *(f16x8*)&XH[(cur * 32 + srow) * LDK + skq] = ph.v;
            *(f16x8*)&XM[(cur * 32 + srow) * LDK + skq] = pm.v;
        }
        __syncthreads();   // the only barrier per step (dbuf makes it safe)

        // prefetch next X step AFTER the barrier: stays in flight across MFMAs
        if (st + 1 < NSTEP) {
            const size_t o = xrow + (size_t)(st + 1) * BK + skq;
            ra = *(const float4*)&x[o];
            rb = *(const float4*)&x[o + 4];
        }

        // ---- compute buf[cur]: 24 MFMA; B straight from L2 ----
        const size_t kb = (size_t)st * BK;
#pragma unroll
        for (int kk = 0; kk < 2; ++kk) {
            f16x8 ah[2], am[2];
#pragma unroll
            for (int i = 0; i < 2; ++i) {
                int r = cur * 32 + i * 16 + fr;
                ah[i] = *(const f16x8*)&XH[r * LDK + kk * 32 + hi * 8];
                am[i] = *(const f16x8*)&XM[r * LDK + kk * 32 + hi * 8];
            }
#pragma unroll
            for (int j = 0; j < 2; ++j) {
                const size_t e = (size_t)(w * 32 + j * 16 + fr);
                const size_t bo = e * DIM + kb + kk * 32 + hi * 8;
                f16x8 bh = *(const f16x8*)&whg[bo];
                f16x8 bm = *(const f16x8*)&wmg[bo];
#pragma unroll
                for (int i = 0; i < 2; ++i) {
                    acc0[i][j] = __builtin_amdgcn_mfma_f32_16x16x32_f16(ah[i], bh, acc0[i][j], 0, 0, 0);
                    acc1[i][j] = __builtin_amdgcn_mfma_f32_16x16x32_f16(ah[i], bm, acc1[i][j], 0, 0, 0);
                    acc1[i][j] = __builtin_amdgcn_mfma_f32_16x16x32_f16(am[i], bh, acc1[i][j], 0, 0, 0);
                }
            }
        }
    }
    __syncthreads();   // protect smem reuse (last compute still reading XH/XM)

    // ---- scores -> LDS (undo w*64 and m*2048 scales) ----
#pragma unroll
    for (int i = 0; i < 2; ++i)
#pragma unroll
        for (int j = 0; j < 2; ++j)
#pragma unroll
            for (int q = 0; q < 4; ++q) {
                int t = i * 16 + hi * 4 + q;
                int e = w * 32 + j * 16 + fr;
                float v = (acc0[i][j][q] + acc1[i][j][q] * (1.0f / 2048.0f)) * (1.0f / 64.0f);
                S[t * 132 + e] = v;
            }
    __syncthreads();

    // ---- top-8 + softmax-over-8: 32 threads, one token each ----
    if (tid < 32) {
        float bs[8]; int bi[8];
#pragma unroll
        for (int r = 0; r < 8; ++r) { bs[r] = -3.0e38f; bi[r] = 0; }
        for (int e = 0; e < NEXP; ++e) {
            float s = S[tid * 132 + e];
            if (s > bs[7]) {
                int pos = 7;
#pragma unroll
                for (int q = 6; q >= 0; q--) pos = (s > bs[q]) ? q : pos;
#pragma unroll
                for (int q = 7; q >= 1; q--) {
                    bool sh = (q > pos);
                    bs[q] = sh ? bs[q - 1] : bs[q];
                    bi[q] = sh ? bi[q - 1] : bi[q];
                }
#pragma unroll
                for (int q = 0; q < 8; q++)
                    if (q == pos) { bs[q] = s; bi[q] = e; }
            }
        }
        float m = bs[0], sum = 0.f, ex[8];
#pragma unroll
        for (int r = 0; r < 8; ++r) { ex[r] = expf(bs[r] - m); sum += ex[r]; }
        float inv = 1.f / fmaxf(sum, 1e-8f);
        const int tok = tok0 + tid;
#pragma unroll
        for (int r = 0; r < 8; ++r) {
            wgt[tok * TOPK + r] = ex[r] * inv;
            sel[tok * TOPK + r] = bi[r];
            atomicAdd(&counts[bi[r]], 1);
        }
    }
}

// ============ stable sort: hist -> (base | block-scan) -> scatter ============
__global__ void hist_kernel(const int* __restrict__ sel, int* __restrict__ bh) {
    __shared__ int h[NEXP];
    const int tid = threadIdx.x, b = blockIdx.x;
    if (tid < NEXP) h[tid] = 0;
    __syncthreads();
    atomicAdd(&h[sel[b * 256 + tid]], 1);
    __syncthreads();
    if (tid < NEXP) bh[tid * NBLK + b] = h[tid];
}

__global__ void base_kernel(const int* __restrict__ counts, int* __restrict__ gbase,
                            float* __restrict__ out) {
    __shared__ int sc[NEXP];
    const int tid = threadIdx.x;   // 128
    int c = counts[tid];
    int v = c;
    sc[tid] = v;
    __syncthreads();
    for (int d = 1; d < NEXP; d <<= 1) {
        int o = (tid >= d) ? sc[tid - d] : 0;
        __syncthreads();
        v += o;
        sc[tid] = v;
        __syncthreads();
    }
    gbase[tid] = v - c;
    out[2 * NFLAT + tid] = (float)c;
}

__global__ void scan_kernel(const int* __restrict__ bh, int* __restrict__ bo) {
    const int e = blockIdx.x, tid = threadIdx.x;   // 512 threads
    const int lane = tid & 63, wid = tid >> 6;
    int v = bh[e * NBLK + tid];
    int sc = v;
#pragma unroll
    for (int d = 1; d < 64; d <<= 1) {
        int o = __shfl_up(sc, d);
        sc += (lane >= d) ? o : 0;
    }
    __shared__ int wsum[8];
    if (lane == 63) wsum[wid] = sc;
    __syncthreads();
    int add = 0;
#pragma unroll
    for (int w = 0; w < 8; w++) add += (w < wid) ? wsum[w] : 0;
    bo[e * NBLK + tid] = sc - v + add;
}

__global__ void scatter_kernel(const int* __restrict__ sel, const float* __restrict__ wgt,
                               const int* __restrict__ bo, const int* __restrict__ gbase,
                               float* __restrict__ out) {
    const int tid = threadIdx.x, b = blockIdx.x;
    const int i = b * 256 + tid;
    const int e = sel[i];
    const int lane = tid & 63, wid = tid >> 6;
    unsigned long long m = ~0ull;
#pragma unroll
    for (int bit = 0; bit < 7; bit++) {
        unsigned long long bal = __ballot((e >> bit) & 1);
        m &= ((e >> bit) & 1) ? bal : ~bal;
    }
    unsigned long long lower = (lane == 0) ? 0ull : (~0ull >> (64 - lane));
    int wrank = __popcll(m & lower);

    __shared__ int wh_[4][NEXP];
    ((int*)wh_)[tid] = 0; ((int*)wh_)[tid + 256] = 0;
    __syncthreads();
    if (wrank == 0) wh_[wid][e] = __popcll(m);
    __syncthreads();
    int off = 0;
#pragma unroll
    for (int w = 0; w < 4; w++) off += (w < wid) ? wh_[w][e] : 0;

    int pos = gbase[e] + bo[e * NBLK + b] + off + wrank;
    out[pos] = wgt[i];
    out[NFLAT + pos] = (float)(i >> 3);
}

extern "C" void kernel_launch(void* const* d_in, const int* in_sizes, int n_in,
                              void* d_out, int out_size, void* d_ws, size_t ws_size,
                              hipStream_t stream) {
    const float* x  = (const float*)d_in[0];
    const float* gw = (const float*)d_in[1];
    float* out = (float*)d_out;
    char*  ws  = (char*)d_ws;

    int*   counts = (int*)(ws + COUNTS_OFF);
    int*   gbase  = (int*)(ws + GBASE_OFF);
    int*   sel    = (int*)(ws + SEL_OFF);
    float* wgt    = (float*)(ws + WGT_OFF);
    int*   bh     = (int*)(ws + BH_OFF);
    int*   bo     = (int*)(ws + BO_OFF);
    f16*   wh     = (f16*)(ws + WH_OFF);
    f16*   wm     = (f16*)(ws + WM_OFF);

    hipMemsetAsync(counts, 0, NEXP * sizeof(int), stream);

    wsplit_kernel<<<NEXP * DIM / 4 / 256, 256, 0, stream>>>(gw, wh, wm);
    fused_kernel<<<NT / BT, 256, 0, stream>>>(x, wh, wm, wgt, sel, counts);
    hist_kernel<<<NBLK, 256, 0, stream>>>(sel, bh);
    base_kernel<<<1, NEXP, 0, stream>>>(counts, gbase, out);
    scan_kernel<<<NEXP, 512, 0, stream>>>(bh, bo);
    scatter_kernel<<<NBLK, 256, 0, stream>>>(sel, wgt, bo, gbase, out);
}

// Round 6
// 185.174 us; speedup vs baseline: 1.7177x; 1.7177x over previous
//
#include <hip/hip_runtime.h>
#include <math.h>

typedef _Float16 f16;
typedef f16 f16x8 __attribute__((ext_vector_type(8)));
typedef float f32x4 __attribute__((ext_vector_type(4)));

#define NT    16384
#define DIM   4096
#define NEXP  128
#define TOPK  8
#define NFLAT (NT * TOPK)   // 131072
#define BT    32            // tokens per fused block
#define NBLK  (NT / BT)     // 512 fused blocks == sort blocks (256 sel entries)
#define BK    64
#define NSTEP (DIM / BK)    // 64

// ---- workspace layout (bytes) ----
#define COUNTS_OFF 0
#define SEL_OFF    1024
#define WGT_OFF    (SEL_OFF + NFLAT * 4)
#define BH_OFF     (WGT_OFF + NFLAT * 4)
#define BO_OFF     (BH_OFF + NEXP * NBLK * 4)
#define WH_OFF     (BO_OFF + NEXP * NBLK * 4)
#define WM_OFF     (WH_OFF + NEXP * DIM * 2)

#define G1P __attribute__((address_space(1)))
#define L3P __attribute__((address_space(3)))

__device__ __forceinline__ void gload_lds16(const void* g, void* l) {
    // dest = wave-uniform LDS base + lane*16 (HW); src = per-lane global addr
    __builtin_amdgcn_global_load_lds((const G1P unsigned int*)g,
                                     (L3P unsigned int*)l, 16, 0, 0);
}

// fp32 -> fp16 high + scaled residual (next ~11 mantissa bits, normal range)
__device__ __forceinline__ void split2(float v, f16& h, f16& m) {
    h = (f16)v;
    m = (f16)((v - (float)h) * 2048.0f);
}

// ============ prologue: split 64*gw into f16 wh/wm (2 MB, L2-resident) ============
__global__ __launch_bounds__(256)
void wsplit_kernel(const float* __restrict__ gw, f16* __restrict__ wh,
                   f16* __restrict__ wm) {
    const int i = (blockIdx.x * 256 + threadIdx.x) * 4;
    float4 v = *(const float4*)&gw[i];
    union { f16 f[4]; uint2 u; } ph, pm;
    split2(v.x * 64.f, ph.f[0], pm.f[0]); split2(v.y * 64.f, ph.f[1], pm.f[1]);
    split2(v.z * 64.f, ph.f[2], pm.f[2]); split2(v.w * 64.f, ph.f[3], pm.f[3]);
    *(uint2*)&wh[i] = ph.u;
    *(uint2*)&wm[i] = pm.u;
}

// ============ fused: scores -> top-8 -> softmax -> sel/wgt/counts/blockhist ============
// 512 thr (8 waves), 32 tok x 128 exp, full K. Wave w owns experts w*16..+15.
// LDS (80 KB): X frag-major dbuf [2][i2][kk2][64]*16B (h:0..8K, m:8K..16K);
//              W frag-major dbuf [2][wave8][h/m][kk2]*1KB at 16K..80K.
__global__ __launch_bounds__(512, 4)
void fused_kernel(const float* __restrict__ x, const f16* __restrict__ whg,
                  const f16* __restrict__ wmg, float* __restrict__ wgt,
                  int* __restrict__ sel, int* __restrict__ counts,
                  int* __restrict__ bh) {
    __shared__ __align__(16) char smem[81920];
    char* WB = smem + 16384;

    const int tid  = threadIdx.x;
    const int tok0 = blockIdx.x * BT;
    const int lane = tid & 63, w = tid >> 6;
    const int fr = lane & 15, hi = lane >> 4;
    // X staging coords: thread -> (row, 4-float k-chunk) -> fragment slot
    const int srow = tid >> 4;                 // 0..31
    const int skq  = (tid & 15) * 4;           // 0..60
    const int xi = srow >> 4, xfr = srow & 15;
    const int xkk = skq >> 5, xhi = (skq >> 3) & 3, xo = skq & 7;  // xo in {0,4}
    const int xwb = ((xi * 2 + xkk) * 64 + (xhi * 16 + xfr)) * 16 + xo * 2;

    f32x4 acc0[2], acc1[2];
#pragma unroll
    for (int i = 0; i < 2; ++i) {
        acc0[i] = (f32x4){0.f, 0.f, 0.f, 0.f};
        acc1[i] = (f32x4){0.f, 0.f, 0.f, 0.f};
    }

    const size_t xrow = (size_t)(tok0 + srow) * DIM;
    const size_t wrow = (size_t)(w * 16 + fr) * DIM + hi * 8;
    float4 ra = *(const float4*)&x[xrow + skq];
    // prologue: W step-0 loads into buf 0
    gload_lds16(whg + wrow,      WB + w * 4096 + 0);
    gload_lds16(whg + wrow + 32, WB + w * 4096 + 1024);
    gload_lds16(wmg + wrow,      WB + w * 4096 + 2048);
    gload_lds16(wmg + wrow + 32, WB + w * 4096 + 3072);

    for (int st = 0; st < NSTEP; ++st) {
        const int cur = st & 1, nxt = cur ^ 1;
        // ---- stage X[st]: split regs -> frag-major LDS[cur] ----
        {
            union { f16 f[4]; uint2 u; } ph, pm;
            split2(ra.x, ph.f[0], pm.f[0]); split2(ra.y, ph.f[1], pm.f[1]);
            split2(ra.z, ph.f[2], pm.f[2]); split2(ra.w, ph.f[3], pm.f[3]);
            *(uint2*)(smem + cur * 4096 + xwb) = ph.u;          // XH
            *(uint2*)(smem + 8192 + cur * 4096 + xwb) = pm.u;   // XM
        }
        __syncthreads();   // drains: X writes (lgkm) + W[cur]/ra loads (vm, ~1 phase old)

        if (st + 1 < NSTEP) {
            // issue W[st+1] -> buf[nxt]: stays in flight across compute[cur]
            const size_t wo = wrow + (size_t)(st + 1) * BK;
            gload_lds16(whg + wo,      WB + nxt * 32768 + w * 4096 + 0);
            gload_lds16(whg + wo + 32, WB + nxt * 32768 + w * 4096 + 1024);
            gload_lds16(wmg + wo,      WB + nxt * 32768 + w * 4096 + 2048);
            gload_lds16(wmg + wo + 32, WB + nxt * 32768 + w * 4096 + 3072);
            // issue X[st+1] global -> regs
            ra = *(const float4*)&x[xrow + (size_t)(st + 1) * BK + skq];
        }

        // ---- compute[cur]: 12 lane-linear ds_read_b128 + 12 MFMA ----
#pragma unroll
        for (int kk = 0; kk < 2; ++kk) {
            f16x8 ah[2], am[2];
#pragma unroll
            for (int i = 0; i < 2; ++i) {
                const int xb = cur * 4096 + ((i * 2 + kk) * 64 + lane) * 16;
                ah[i] = *(const f16x8*)(smem + xb);
                am[i] = *(const f16x8*)(smem + 8192 + xb);
            }
            const int wb = cur * 32768 + w * 4096 + kk * 1024 + lane * 16;
            f16x8 bhf = *(const f16x8*)(WB + wb);
            f16x8 bmf = *(const f16x8*)(WB + wb + 2048);
#pragma unroll
            for (int i = 0; i < 2; ++i) {
                acc0[i] = __builtin_amdgcn_mfma_f32_16x16x32_f16(ah[i], bhf, acc0[i], 0, 0, 0);
                acc1[i] = __builtin_amdgcn_mfma_f32_16x16x32_f16(ah[i], bmf, acc1[i], 0, 0, 0);
                acc1[i] = __builtin_amdgcn_mfma_f32_16x16x32_f16(am[i], bhf, acc1[i], 0, 0, 0);
            }
        }
    }
    __syncthreads();

    // ---- scores -> LDS S[32][132] (undo w*64 and m*2048 scales) ----
    float* S = (float*)smem;
    int*   h = (int*)(smem + 18432);
#pragma unroll
    for (int i = 0; i < 2; ++i)
#pragma unroll
        for (int q = 0; q < 4; ++q) {
            int t = i * 16 + hi * 4 + q;
            int e = w * 16 + fr;
            S[t * 132 + e] = (acc0[i][q] + acc1[i][q] * (1.0f / 2048.0f)) * (1.0f / 64.0f);
        }
    if (tid < NEXP) h[tid] = 0;
    __syncthreads();

    // ---- top-8 + softmax-over-8: 32 threads, one token each ----
    if (tid < BT) {
        float bs[8]; int bi[8];
#pragma unroll
        for (int r = 0; r < 8; ++r) { bs[r] = -3.0e38f; bi[r] = 0; }
        for (int e = 0; e < NEXP; ++e) {
            float s = S[tid * 132 + e];
            if (s > bs[7]) {
                int pos = 7;
#pragma unroll
                for (int q = 6; q >= 0; q--) pos = (s > bs[q]) ? q : pos;
#pragma unroll
                for (int q = 7; q >= 1; q--) {
                    bool sh = (q > pos);
                    bs[q] = sh ? bs[q - 1] : bs[q];
                    bi[q] = sh ? bi[q - 1] : bi[q];
                }
#pragma unroll
                for (int q = 0; q < 8; q++)
                    if (q == pos) { bs[q] = s; bi[q] = e; }
            }
        }
        float m = bs[0], sum = 0.f, ex[8];
#pragma unroll
        for (int r = 0; r < 8; ++r) { ex[r] = expf(bs[r] - m); sum += ex[r]; }
        float inv = 1.f / fmaxf(sum, 1e-8f);
        const int tok = tok0 + tid;
#pragma unroll
        for (int r = 0; r < 8; ++r) {
            wgt[tok * TOPK + r] = ex[r] * inv;
            sel[tok * TOPK + r] = bi[r];
            atomicAdd(&h[bi[r]], 1);
        }
    }
    __syncthreads();
    if (tid < NEXP) {
        int c = h[tid];
        bh[tid * NBLK + blockIdx.x] = c;   // per-block histogram (this block == sort block)
        if (c) atomicAdd(&counts[tid], c);
    }
}

// ============ scan: expert bases + per-expert exclusive block-scan ============
__global__ void scan_kernel(const int* __restrict__ bh, const int* __restrict__ counts,
                            int* __restrict__ bo, float* __restrict__ out) {
    const int e = blockIdx.x, tid = threadIdx.x;   // 128 blocks x 512 thr
    __shared__ int pre[NEXP];
    __shared__ int wsum[8];
    if (tid < NEXP) pre[tid] = counts[tid];
    __syncthreads();
#pragma unroll
    for (int d = 1; d < NEXP; d <<= 1) {
        int o = (tid < NEXP && tid >= d) ? pre[tid - d] : 0;
        __syncthreads();
        if (tid < NEXP) pre[tid] += o;
        __syncthreads();
    }
    const int gb = (e == 0) ? 0 : pre[e - 1];
    if (tid == 0) out[2 * NFLAT + e] = (float)counts[e];

    const int lane = tid & 63, wid = tid >> 6;
    int v = bh[e * NBLK + tid];
    int sc = v;
#pragma unroll
    for (int d = 1; d < 64; d <<= 1) {
        int o = __shfl_up(sc, d);
        sc += (lane >= d) ? o : 0;
    }
    if (lane == 63) wsum[wid] = sc;
    __syncthreads();
    int add = 0;
#pragma unroll
    for (int ww = 0; ww < 8; ww++) add += (ww < wid) ? wsum[ww] : 0;
    bo[e * NBLK + tid] = gb + sc - v + add;   // global exclusive offset baked in
}

// ============ scatter: stable in-block rank via 7 ballots ============
__global__ void scatter_kernel(const int* __restrict__ sel, const float* __restrict__ wgt,
                               const int* __restrict__ bo, float* __restrict__ out) {
    const int tid = threadIdx.x, b = blockIdx.x;
    const int i = b * 256 + tid;
    const int e = sel[i];
    const int lane = tid & 63, wid = tid >> 6;
    unsigned long long m = ~0ull;
#pragma unroll
    for (int bit = 0; bit < 7; bit++) {
        unsigned long long bal = __ballot((e >> bit) & 1);
        m &= ((e >> bit) & 1) ? bal : ~bal;
    }
    unsigned long long lower = (lane == 0) ? 0ull : (~0ull >> (64 - lane));
    int wrank = __popcll(m & lower);

    __shared__ int wh_[4][NEXP];
    ((int*)wh_)[tid] = 0; ((int*)wh_)[tid + 256] = 0;
    __syncthreads();
    if (wrank == 0) wh_[wid][e] = __popcll(m);
    __syncthreads();
    int off = 0;
#pragma unroll
    for (int ww = 0; ww < 4; ww++) off += (ww < wid) ? wh_[ww][e] : 0;

    int pos = bo[e * NBLK + b] + off + wrank;
    out[pos] = wgt[i];
    out[NFLAT + pos] = (float)(i >> 3);
}

extern "C" void kernel_launch(void* const* d_in, const int* in_sizes, int n_in,
                              void* d_out, int out_size, void* d_ws, size_t ws_size,
                              hipStream_t stream) {
    const float* x  = (const float*)d_in[0];
    const float* gw = (const float*)d_in[1];
    float* out = (float*)d_out;
    char*  ws  = (char*)d_ws;

    int*   counts = (int*)(ws + COUNTS_OFF);
    int*   sel    = (int*)(ws + SEL_OFF);
    float* wgt    = (float*)(ws + WGT_OFF);
    int*   bh     = (int*)(ws + BH_OFF);
    int*   bo     = (int*)(ws + BO_OFF);
    f16*   wh     = (f16*)(ws + WH_OFF);
    f16*   wm     = (f16*)(ws + WM_OFF);

    hipMemsetAsync(counts, 0, NEXP * sizeof(int), stream);

    wsplit_kernel<<<NEXP * DIM / 4 / 256, 256, 0, stream>>>(gw, wh, wm);
    fused_kernel<<<NBLK, 512, 0, stream>>>(x, wh, wm, wgt, sel, counts, bh);
    scan_kernel<<<NEXP, 512, 0, stream>>>(bh, counts, bo, out);
    scatter_kernel<<<NBLK, 256, 0, stream>>>(sel, wgt, bo, out);
}

// Round 7
// 179.748 us; speedup vs baseline: 1.7696x; 1.0302x over previous
//
#include <hip/hip_runtime.h>
#include <math.h>

typedef _Float16 f16;
typedef f16 f16x8 __attribute__((ext_vector_type(8)));
typedef float f32x4 __attribute__((ext_vector_type(4)));

#define NT    16384
#define DIM   4096
#define NEXP  128
#define TOPK  8
#define NFLAT (NT * TOPK)   // 131072
#define BT    32            // tokens per fused block
#define NBLK  (NT / BT)     // 512 fused blocks == sort blocks
#define BK    64
#define NSTEP (DIM / BK)    // 64

// ---- workspace layout (bytes) ----
#define COUNTS_OFF 0
#define SEL_OFF    1024
#define WGT_OFF    (SEL_OFF + NFLAT * 4)
#define BH_OFF     (WGT_OFF + NFLAT * 4)
#define BO_OFF     (BH_OFF + NEXP * NBLK * 4)
#define WH_OFF     (BO_OFF + NEXP * NBLK * 4)
#define WM_OFF     (WH_OFF + NEXP * DIM * 2)

#define G1P __attribute__((address_space(1)))
#define L3P __attribute__((address_space(3)))

__device__ __forceinline__ void gload_lds16(const void* g, void* l) {
    __builtin_amdgcn_global_load_lds((const G1P unsigned int*)g,
                                     (L3P unsigned int*)l, 16, 0, 0);
}

// fp32 -> fp16 high + scaled residual (next ~11 mantissa bits, normal range)
__device__ __forceinline__ void split2(float v, f16& h, f16& m) {
    h = (f16)v;
    m = (f16)((v - (float)h) * 2048.0f);
}

// ============ prologue: split 64*gw into f16 wh/wm (2 MB, L2-resident) ============
__global__ __launch_bounds__(256)
void wsplit_kernel(const float* __restrict__ gw, f16* __restrict__ wh,
                   f16* __restrict__ wm) {
    const int i = (blockIdx.x * 256 + threadIdx.x) * 4;
    float4 v = *(const float4*)&gw[i];
    union { f16 f[4]; uint2 u; } ph, pm;
    split2(v.x * 64.f, ph.f[0], pm.f[0]); split2(v.y * 64.f, ph.f[1], pm.f[1]);
    split2(v.z * 64.f, ph.f[2], pm.f[2]); split2(v.w * 64.f, ph.f[3], pm.f[3]);
    *(uint2*)&wh[i] = ph.u;
    *(uint2*)&wm[i] = pm.u;
}

// ============ fused: scores -> top-8 -> softmax -> sel/wgt/counts/blockhist ============
// 512 thr (8 waves), 32 tok x 128 exp, full K. Wave w owns experts w*16..+15.
// Pipeline: raw s_barrier + counted vmcnt (never 0 in main loop); x prefetch
// 2 steps deep in regs; W dbuf via global_load_lds 1 step deep (wave-private).
__global__ __launch_bounds__(512, 4)
void fused_kernel(const float* __restrict__ x, const f16* __restrict__ whg,
                  const f16* __restrict__ wmg, float* __restrict__ wgt,
                  int* __restrict__ sel, int* __restrict__ counts,
                  int* __restrict__ bh) {
    __shared__ __align__(16) char smem[81920];
    char* WB = smem + 16384;

    const int tid  = threadIdx.x;
    const int tok0 = blockIdx.x * BT;
    const int lane = tid & 63, w = tid >> 6;
    const int fr = lane & 15, hi = lane >> 4;
    // X staging coords: thread -> (row, 4-float k-chunk) -> swizzled frag slot
    const int srow = tid >> 4;                 // 0..31
    const int skq  = (tid & 15) * 4;           // 0..60
    const int xi = srow >> 4, xfr = srow & 15;
    const int xkk = skq >> 5, xhi = (skq >> 3) & 3, xo = skq & 7;  // xo in {0,4}
    const int slot = xhi * 16 + xfr;
    const int xwb = ((xi * 2 + xkk) * 64 + (slot ^ (xhi << 1))) * 16 + xo * 2;
    // swizzled read lane term (same involution: s ^= (s>>4)<<1)
    const int lxs = (lane ^ ((lane >> 4) << 1)) * 16;

    f32x4 acc0[2], acc1[2];
#pragma unroll
    for (int i = 0; i < 2; ++i) {
        acc0[i] = (f32x4){0.f, 0.f, 0.f, 0.f};
        acc1[i] = (f32x4){0.f, 0.f, 0.f, 0.f};
    }

    const size_t xrow = (size_t)(tok0 + srow) * DIM;
    const size_t wrow = (size_t)(w * 16 + fr) * DIM + hi * 8;

#define X_PREF(RA, SI) RA = *(const float4*)&x[xrow + (size_t)(SI) * BK + skq];
#define W_PREF(SI, B) { \
    const size_t wo = wrow + (size_t)(SI) * BK; \
    gload_lds16(whg + wo,      WB + (B) * 32768 + w * 4096 + 0); \
    gload_lds16(whg + wo + 32, WB + (B) * 32768 + w * 4096 + 1024); \
    gload_lds16(wmg + wo,      WB + (B) * 32768 + w * 4096 + 2048); \
    gload_lds16(wmg + wo + 32, WB + (B) * 32768 + w * 4096 + 3072); }
#define STAGE(CUR, RA) { \
    union { f16 f[4]; uint2 u; } ph, pm; \
    split2(RA.x, ph.f[0], pm.f[0]); split2(RA.y, ph.f[1], pm.f[1]); \
    split2(RA.z, ph.f[2], pm.f[2]); split2(RA.w, ph.f[3], pm.f[3]); \
    *(uint2*)(smem + (CUR) * 4096 + xwb) = ph.u; \
    *(uint2*)(smem + 8192 + (CUR) * 4096 + xwb) = pm.u; }
#define COMPUTE(CUR) { \
    _Pragma("unroll") \
    for (int kk = 0; kk < 2; ++kk) { \
        f16x8 ah[2], am[2]; \
        _Pragma("unroll") \
        for (int i = 0; i < 2; ++i) { \
            const int xb = (CUR) * 4096 + (i * 2 + kk) * 1024 + lxs; \
            ah[i] = *(const f16x8*)(smem + xb); \
            am[i] = *(const f16x8*)(smem + 8192 + xb); \
        } \
        const int wb = (CUR) * 32768 + w * 4096 + kk * 1024 + lane * 16; \
        f16x8 bhf = *(const f16x8*)(WB + wb); \
        f16x8 bmf = *(const f16x8*)(WB + wb + 2048); \
        _Pragma("unroll") \
        for (int i = 0; i < 2; ++i) { \
            acc0[i] = __builtin_amdgcn_mfma_f32_16x16x32_f16(ah[i], bhf, acc0[i], 0, 0, 0); \
            acc1[i] = __builtin_amdgcn_mfma_f32_16x16x32_f16(ah[i], bmf, acc1[i], 0, 0, 0); \
            acc1[i] = __builtin_amdgcn_mfma_f32_16x16x32_f16(am[i], bhf, acc1[i], 0, 0, 0); \
        } \
    } }
#define STEP(CUR, RA, PX, PW, SI, VMSTR) { \
    STAGE(CUR, RA); \
    asm volatile("s_waitcnt lgkmcnt(0)" ::: "memory"); \
    __builtin_amdgcn_s_barrier(); \
    if (PX) { X_PREF(RA, (SI) + 2); } \
    if (PW) { W_PREF((SI) + 1, (CUR) ^ 1); } \
    asm volatile("s_waitcnt vmcnt(" VMSTR ")" ::: "memory"); \
    __builtin_amdgcn_sched_barrier(0); \
    __builtin_amdgcn_s_setprio(1); \
    COMPUTE(CUR); \
    __builtin_amdgcn_s_setprio(0); }

    // prologue: x[0], x[1] -> regs; W[0] -> buf0
    float4 ra0, ra1;
    X_PREF(ra0, 0);
    X_PREF(ra1, 1);
    W_PREF(0, 0);

    // steady state queue at compute: [x_{st+1}, W_st*4, x_{st+2}, W_{st+1}*4]
    // -> vmcnt(5) retires W_st (and x_{st+1}) while keeping 5 in flight.
    for (int st = 0; st < 62; st += 2) {
        STEP(0, ra0, 1, 1, st, "5");
        STEP(1, ra1, 1, 1, st + 1, "5");
    }
    STEP(0, ra0, 0, 1, 62, "4");   // queue [x63,W62*4,W63*4] -> retire W62
    STEP(1, ra1, 0, 0, 63, "0");   // queue [W63*4] -> drain

    __syncthreads();   // full drain; smem reused below

    // ---- scores -> LDS S[32][132] (undo w*64 and m*2048 scales) ----
    float* S = (float*)smem;
    int*   h = (int*)(smem + 18432);
#pragma unroll
    for (int i = 0; i < 2; ++i)
#pragma unroll
        for (int q = 0; q < 4; ++q) {
            int t = i * 16 + hi * 4 + q;
            int e = w * 16 + fr;
            S[t * 132 + e] = (acc0[i][q] + acc1[i][q] * (1.0f / 2048.0f)) * (1.0f / 64.0f);
        }
    if (tid < NEXP) h[tid] = 0;
    __syncthreads();

    // ---- top-8 + softmax-over-8: 32 threads, one token each ----
    if (tid < BT) {
        float bs[8]; int bi[8];
#pragma unroll
        for (int r = 0; r < 8; ++r) { bs[r] = -3.0e38f; bi[r] = 0; }
        for (int e = 0; e < NEXP; ++e) {
            float s = S[tid * 132 + e];
            if (s > bs[7]) {
                int pos = 7;
#pragma unroll
                for (int q = 6; q >= 0; q--) pos = (s > bs[q]) ? q : pos;
#pragma unroll
                for (int q = 7; q >= 1; q--) {
                    bool sh = (q > pos);
                    bs[q] = sh ? bs[q - 1] : bs[q];
                    bi[q] = sh ? bi[q - 1] : bi[q];
                }
#pragma unroll
                for (int q = 0; q < 8; q++)
                    if (q == pos) { bs[q] = s; bi[q] = e; }
            }
        }
        float m = bs[0], sum = 0.f, ex[8];
#pragma unroll
        for (int r = 0; r < 8; ++r) { ex[r] = expf(bs[r] - m); sum += ex[r]; }
        float inv = 1.f / fmaxf(sum, 1e-8f);
        const int tok = tok0 + tid;
#pragma unroll
        for (int r = 0; r < 8; ++r) {
            wgt[tok * TOPK + r] = ex[r] * inv;
            sel[tok * TOPK + r] = bi[r];
            atomicAdd(&h[bi[r]], 1);
        }
    }
    __syncthreads();
    if (tid < NEXP) {
        int c = h[tid];
        bh[tid * NBLK + blockIdx.x] = c;
        if (c) atomicAdd(&counts[tid], c);
    }
}

// ============ scan: expert bases + per-expert exclusive block-scan ============
__global__ void scan_kernel(const int* __restrict__ bh, const int* __restrict__ counts,
                            int* __restrict__ bo, float* __restrict__ out) {
    const int e = blockIdx.x, tid = threadIdx.x;   // 128 blocks x 512 thr
    __shared__ int pre[NEXP];
    __shared__ int wsum[8];
    if (tid < NEXP) pre[tid] = counts[tid];
    __syncthreads();
#pragma unroll
    for (int d = 1; d < NEXP; d <<= 1) {
        int o = (tid < NEXP && tid >= d) ? pre[tid - d] : 0;
        __syncthreads();
        if (tid < NEXP) pre[tid] += o;
        __syncthreads();
    }
    const int gb = (e == 0) ? 0 : pre[e - 1];
    if (tid == 0) out[2 * NFLAT + e] = (float)counts[e];

    const int lane = tid & 63, wid = tid >> 6;
    int v = bh[e * NBLK + tid];
    int sc = v;
#pragma unroll
    for (int d = 1; d < 64; d <<= 1) {
        int o = __shfl_up(sc, d);
        sc += (lane >= d) ? o : 0;
    }
    if (lane == 63) wsum[wid] = sc;
    __syncthreads();
    int add = 0;
#pragma unroll
    for (int ww = 0; ww < 8; ww++) add += (ww < wid) ? wsum[ww] : 0;
    bo[e * NBLK + tid] = gb + sc - v + add;
}

// ============ scatter: stable in-block rank via 7 ballots ============
__global__ void scatter_kernel(const int* __restrict__ sel, const float* __restrict__ wgt,
                               const int* __restrict__ bo, float* __restrict__ out) {
    const int tid = threadIdx.x, b = blockIdx.x;
    const int i = b * 256 + tid;
    const int e = sel[i];
    const int lane = tid & 63, wid = tid >> 6;
    unsigned long long m = ~0ull;
#pragma unroll
    for (int bit = 0; bit < 7; bit++) {
        unsigned long long bal = __ballot((e >> bit) & 1);
        m &= ((e >> bit) & 1) ? bal : ~bal;
    }
    unsigned long long lower = (lane == 0) ? 0ull : (~0ull >> (64 - lane));
    int wrank = __popcll(m & lower);

    __shared__ int wh_[4][NEXP];
    ((int*)wh_)[tid] = 0; ((int*)wh_)[tid + 256] = 0;
    __syncthreads();
    if (wrank == 0) wh_[wid][e] = __popcll(m);
    __syncthreads();
    int off = 0;
#pragma unroll
    for (int ww = 0; ww < 4; ww++) off += (ww < wid) ? wh_[ww][e] : 0;

    int pos = bo[e * NBLK + b] + off + wrank;
    out[pos] = wgt[i];
    out[NFLAT + pos] = (float)(i >> 3);
}

extern "C" void kernel_launch(void* const* d_in, const int* in_sizes, int n_in,
                              void* d_out, int out_size, void* d_ws, size_t ws_size,
                              hipStream_t stream) {
    const float* x  = (const float*)d_in[0];
    const float* gw = (const float*)d_in[1];
    float* out = (float*)d_out;
    char*  ws  = (char*)d_ws;

    int*   counts = (int*)(ws + COUNTS_OFF);
    int*   sel    = (int*)(ws + SEL_OFF);
    float* wgt    = (float*)(ws + WGT_OFF);
    int*   bh     = (int*)(ws + BH_OFF);
    int*   bo     = (int*)(ws + BO_OFF);
    f16*   wh     = (f16*)(ws + WH_OFF);
    f16*   wm     = (f16*)(ws + WM_OFF);

    hipMemsetAsync(counts, 0, NEXP * sizeof(int), stream);

    wsplit_kernel<<<NEXP * DIM / 4 / 256, 256, 0, stream>>>(gw, wh, wm);
    fused_kernel<<<NBLK, 512, 0, stream>>>(x, wh, wm, wgt, sel, counts, bh);
    scan_kernel<<<NEXP, 512, 0, stream>>>(bh, counts, bo, out);
    scatter_kernel<<<NBLK, 256, 0, stream>>>(sel, wgt, bo, out);
}

// Round 8
// 127.871 us; speedup vs baseline: 2.4875x; 1.4057x over previous
//
#include <hip/hip_runtime.h>
#include <math.h>

typedef _Float16 f16;
typedef f16 f16x8 __attribute__((ext_vector_type(8)));
typedef float f32x4 __attribute__((ext_vector_type(4)));

#define NT    16384
#define DIM   4096
#define NEXP  128
#define TOPK  8
#define NFLAT (NT * TOPK)   // 131072
#define BT    32            // tokens per fused block
#define NBLK  (NT / BT)     // 512 fused blocks == sort blocks
#define BK    64
#define NSTEP (DIM / BK)    // 64

// ---- workspace layout (bytes) ----
#define COUNTS_OFF 0
#define SEL_OFF    1024
#define WGT_OFF    (SEL_OFF + NFLAT * 4)
#define BH_OFF     (WGT_OFF + NFLAT * 4)
#define BO_OFF     (BH_OFF + NEXP * NBLK * 4)
#define WPK_OFF    (BO_OFF + NEXP * NBLK * 4)   // 2 MB packed W (f16 h+m, frag order)

#define G1P __attribute__((address_space(1)))
#define L3P __attribute__((address_space(3)))

__device__ __forceinline__ void gload_lds16(const void* g, void* l) {
    __builtin_amdgcn_global_load_lds((const G1P unsigned int*)g,
                                     (L3P unsigned int*)l, 16, 0, 0);
}

// fp32 -> fp16 high + scaled residual (next ~11 mantissa bits, normal range)
__device__ __forceinline__ void split2(float v, f16& h, f16& m) {
    h = (f16)v;
    m = (f16)((v - (float)h) * 2048.0f);
}

// ============ prologue: pack 64*gw into fragment-ordered f16 chunks ============
// wpk[(st*8+w)*4096 + c*1024 + lane*16] : c0=h,kk0  c1=h,kk1  c2=m,kk0  c3=m,kk1
// content(lane l) = halves of 64*gw[w*16+(l&15)][st*64 + kk*32 + (l>>4)*8 ..+7]
__global__ __launch_bounds__(256)
void wsplit_kernel(const float* __restrict__ gw, char* __restrict__ wpk) {
    const int t = blockIdx.x * 256 + threadIdx.x;    // 65536 threads
    const int l = t & 63, kkc = (t >> 6) & 1, w = (t >> 7) & 7, st = t >> 10;
    const int e = w * 16 + (l & 15);
    const int k0 = st * 64 + kkc * 32 + (l >> 4) * 8;
    float4 a = *(const float4*)&gw[e * 4096 + k0];
    float4 b = *(const float4*)&gw[e * 4096 + k0 + 4];
    union { f16 f[8]; uint4 u; } ph, pm;
    split2(a.x * 64.f, ph.f[0], pm.f[0]); split2(a.y * 64.f, ph.f[1], pm.f[1]);
    split2(a.z * 64.f, ph.f[2], pm.f[2]); split2(a.w * 64.f, ph.f[3], pm.f[3]);
    split2(b.x * 64.f, ph.f[4], pm.f[4]); split2(b.y * 64.f, ph.f[5], pm.f[5]);
    split2(b.z * 64.f, ph.f[6], pm.f[6]); split2(b.w * 64.f, ph.f[7], pm.f[7]);
    const size_t base = ((size_t)(st * 8 + w) * 4 + kkc) * 1024 + l * 16;
    *(uint4*)(wpk + base)        = ph.u;   // h chunk (c = kkc)
    *(uint4*)(wpk + base + 2048) = pm.u;   // m chunk (c = kkc+2)
}

// ============ fused: scores -> top-8 -> softmax -> sel/wgt/counts/blockhist ============
// 512 thr (8 waves), 32 tok x 128 exp, full K. Wave w owns experts w*16..+15.
// Pipeline: raw s_barrier + counted vmcnt (never 0 in main loop); x prefetch
// 2 steps deep in regs; W dbuf via coalesced 1KB global_load_lds, 1 step deep.
__global__ __launch_bounds__(512, 4)
void fused_kernel(const float* __restrict__ x, const char* __restrict__ wpk,
                  float* __restrict__ wgt, int* __restrict__ sel,
                  int* __restrict__ counts, int* __restrict__ bh) {
    __shared__ __align__(16) char smem[81920];
    char* WB = smem + 16384;

    const int tid  = threadIdx.x;
    const int tok0 = blockIdx.x * BT;
    const int lane = tid & 63, w = tid >> 6;
    const int fr = lane & 15, hi = lane >> 4;
    // X staging coords: thread -> (row, 4-float k-chunk) -> swizzled frag slot
    const int srow = tid >> 4;                 // 0..31
    const int skq  = (tid & 15) * 4;           // 0..60
    const int xi = srow >> 4, xfr = srow & 15;
    const int xkk = skq >> 5, xhi = (skq >> 3) & 3, xo = skq & 7;  // xo in {0,4}
    const int slot = xhi * 16 + xfr;
    const int xwb = ((xi * 2 + xkk) * 64 + (slot ^ (xhi << 1))) * 16 + xo * 2;
    // swizzled read lane term (same involution: s ^= (s>>4)<<1)
    const int lxs = (lane ^ ((lane >> 4) << 1)) * 16;

    f32x4 acc0[2], acc1[2];
#pragma unroll
    for (int i = 0; i < 2; ++i) {
        acc0[i] = (f32x4){0.f, 0.f, 0.f, 0.f};
        acc1[i] = (f32x4){0.f, 0.f, 0.f, 0.f};
    }

    const size_t xrow = (size_t)(tok0 + srow) * DIM;

#define X_PREF(RA, SI) RA = *(const float4*)&x[xrow + (size_t)(SI) * BK + skq];
#define W_PREF(SI, B) { \
    const char* wsrc = wpk + ((size_t)(SI) * 8 + w) * 4096 + lane * 16; \
    char* wdst = WB + (B) * 32768 + w * 4096; \
    gload_lds16(wsrc,        wdst); \
    gload_lds16(wsrc + 1024, wdst + 1024); \
    gload_lds16(wsrc + 2048, wdst + 2048); \
    gload_lds16(wsrc + 3072, wdst + 3072); }
#define STAGE(CUR, RA) { \
    union { f16 f[4]; uint2 u; } ph, pm; \
    split2(RA.x, ph.f[0], pm.f[0]); split2(RA.y, ph.f[1], pm.f[1]); \
    split2(RA.z, ph.f[2], pm.f[2]); split2(RA.w, ph.f[3], pm.f[3]); \
    *(uint2*)(smem + (CUR) * 4096 + xwb) = ph.u; \
    *(uint2*)(smem + 8192 + (CUR) * 4096 + xwb) = pm.u; }
#define COMPUTE(CUR) { \
    _Pragma("unroll") \
    for (int kk = 0; kk < 2; ++kk) { \
        f16x8 ah[2], am[2]; \
        _Pragma("unroll") \
        for (int i = 0; i < 2; ++i) { \
            const int xb = (CUR) * 4096 + (i * 2 + kk) * 1024 + lxs; \
            ah[i] = *(const f16x8*)(smem + xb); \
            am[i] = *(const f16x8*)(smem + 8192 + xb); \
        } \
        const int wb = (CUR) * 32768 + w * 4096 + kk * 1024 + lane * 16; \
        f16x8 bhf = *(const f16x8*)(WB + wb); \
        f16x8 bmf = *(const f16x8*)(WB + wb + 2048); \
        _Pragma("unroll") \
        for (int i = 0; i < 2; ++i) { \
            acc0[i] = __builtin_amdgcn_mfma_f32_16x16x32_f16(ah[i], bhf, acc0[i], 0, 0, 0); \
            acc1[i] = __builtin_amdgcn_mfma_f32_16x16x32_f16(ah[i], bmf, acc1[i], 0, 0, 0); \
            acc1[i] = __builtin_amdgcn_mfma_f32_16x16x32_f16(am[i], bhf, acc1[i], 0, 0, 0); \
        } \
    } }
#define STEP(CUR, RA, PX, PW, SI, VMSTR) { \
    STAGE(CUR, RA); \
    asm volatile("s_waitcnt lgkmcnt(0)" ::: "memory"); \
    __builtin_amdgcn_s_barrier(); \
    if (PX) { X_PREF(RA, (SI) + 2); } \
    if (PW) { W_PREF((SI) + 1, (CUR) ^ 1); } \
    asm volatile("s_waitcnt vmcnt(" VMSTR ")" ::: "memory"); \
    __builtin_amdgcn_sched_barrier(0); \
    __builtin_amdgcn_s_setprio(1); \
    COMPUTE(CUR); \
    __builtin_amdgcn_s_setprio(0); }

    // prologue: x[0], x[1] -> regs; W[0] -> buf0
    float4 ra0, ra1;
    X_PREF(ra0, 0);
    X_PREF(ra1, 1);
    W_PREF(0, 0);

    // steady state queue at compute: [x_{st+1}, W_st*4, x_{st+2}, W_{st+1}*4]
    // -> vmcnt(5) retires W_st (and x_{st+1}) while keeping 5 in flight.
    for (int st = 0; st < 62; st += 2) {
        STEP(0, ra0, 1, 1, st, "5");
        STEP(1, ra1, 1, 1, st + 1, "5");
    }
    STEP(0, ra0, 0, 1, 62, "4");   // queue [x63,W62*4,W63*4] -> retire W62
    STEP(1, ra1, 0, 0, 63, "0");   // queue [W63*4] -> drain

    __syncthreads();   // full drain; smem reused below

    // ---- scores -> LDS S[32][132] (undo w*64 and m*2048 scales) ----
    float* S = (float*)smem;
    int*   h = (int*)(smem + 18432);
#pragma unroll
    for (int i = 0; i < 2; ++i)
#pragma unroll
        for (int q = 0; q < 4; ++q) {
            int t = i * 16 + hi * 4 + q;
            int e = w * 16 + fr;
            S[t * 132 + e] = (acc0[i][q] + acc1[i][q] * (1.0f / 2048.0f)) * (1.0f / 64.0f);
        }
    if (tid < NEXP) h[tid] = 0;
    __syncthreads();

    // ---- top-8 + softmax-over-8: 32 threads, one token each ----
    if (tid < BT) {
        float bs[8]; int bi[8];
#pragma unroll
        for (int r = 0; r < 8; ++r) { bs[r] = -3.0e38f; bi[r] = 0; }
        for (int e = 0; e < NEXP; ++e) {
            float s = S[tid * 132 + e];
            if (s > bs[7]) {
                int pos = 7;
#pragma unroll
                for (int q = 6; q >= 0; q--) pos = (s > bs[q]) ? q : pos;
#pragma unroll
                for (int q = 7; q >= 1; q--) {
                    bool sh = (q > pos);
                    bs[q] = sh ? bs[q - 1] : bs[q];
                    bi[q] = sh ? bi[q - 1] : bi[q];
                }
#pragma unroll
                for (int q = 0; q < 8; q++)
                    if (q == pos) { bs[q] = s; bi[q] = e; }
            }
        }
        float m = bs[0], sum = 0.f, ex[8];
#pragma unroll
        for (int r = 0; r < 8; ++r) { ex[r] = expf(bs[r] - m); sum += ex[r]; }
        float inv = 1.f / fmaxf(sum, 1e-8f);
        const int tok = tok0 + tid;
#pragma unroll
        for (int r = 0; r < 8; ++r) {
            wgt[tok * TOPK + r] = ex[r] * inv;
            sel[tok * TOPK + r] = bi[r];
            atomicAdd(&h[bi[r]], 1);
        }
    }
    __syncthreads();
    if (tid < NEXP) {
        int c = h[tid];
        bh[tid * NBLK + blockIdx.x] = c;
        if (c) atomicAdd(&counts[tid], c);
    }
}

// ============ scan: expert bases + per-expert exclusive block-scan ============
__global__ void scan_kernel(const int* __restrict__ bh, const int* __restrict__ counts,
                            int* __restrict__ bo, float* __restrict__ out) {
    const int e = blockIdx.x, tid = threadIdx.x;   // 128 blocks x 512 thr
    __shared__ int pre[NEXP];
    __shared__ int wsum[8];
    if (tid < NEXP) pre[tid] = counts[tid];
    __syncthreads();
#pragma unroll
    for (int d = 1; d < NEXP; d <<= 1) {
        int o = (tid < NEXP && tid >= d) ? pre[tid - d] : 0;
        __syncthreads();
        if (tid < NEXP) pre[tid] += o;
        __syncthreads();
    }
    const int gb = (e == 0) ? 0 : pre[e - 1];
    if (tid == 0) out[2 * NFLAT + e] = (float)counts[e];

    const int lane = tid & 63, wid = tid >> 6;
    int v = bh[e * NBLK + tid];
    int sc = v;
#pragma unroll
    for (int d = 1; d < 64; d <<= 1) {
        int o = __shfl_up(sc, d);
        sc += (lane >= d) ? o : 0;
    }
    if (lane == 63) wsum[wid] = sc;
    __syncthreads();
    int add = 0;
#pragma unroll
    for (int ww = 0; ww < 8; ww++) add += (ww < wid) ? wsum[ww] : 0;
    bo[e * NBLK + tid] = gb + sc - v + add;
}

// ============ scatter: stable in-block rank via 7 ballots ============
__global__ void scatter_kernel(const int* __restrict__ sel, const float* __restrict__ wgt,
                               const int* __restrict__ bo, float* __restrict__ out) {
    const int tid = threadIdx.x, b = blockIdx.x;
    const int i = b * 256 + tid;
    const int e = sel[i];
    const int lane = tid & 63, wid = tid >> 6;
    unsigned long long m = ~0ull;
#pragma unroll
    for (int bit = 0; bit < 7; bit++) {
        unsigned long long bal = __ballot((e >> bit) & 1);
        m &= ((e >> bit) & 1) ? bal : ~bal;
    }
    unsigned long long lower = (lane == 0) ? 0ull : (~0ull >> (64 - lane));
    int wrank = __popcll(m & lower);

    __shared__ int wh_[4][NEXP];
    ((int*)wh_)[tid] = 0; ((int*)wh_)[tid + 256] = 0;
    __syncthreads();
    if (wrank == 0) wh_[wid][e] = __popcll(m);
    __syncthreads();
    int off = 0;
#pragma unroll
    for (int ww = 0; ww < 4; ww++) off += (ww < wid) ? wh_[ww][e] : 0;

    int pos = bo[e * NBLK + b] + off + wrank;
    out[pos] = wgt[i];
    out[NFLAT + pos] = (float)(i >> 3);
}

extern "C" void kernel_launch(void* const* d_in, const int* in_sizes, int n_in,
                              void* d_out, int out_size, void* d_ws, size_t ws_size,
                              hipStream_t stream) {
    const float* x  = (const float*)d_in[0];
    const float* gw = (const float*)d_in[1];
    float* out = (float*)d_out;
    char*  ws  = (char*)d_ws;

    int*   counts = (int*)(ws + COUNTS_OFF);
    int*   sel    = (int*)(ws + SEL_OFF);
    float* wgt    = (float*)(ws + WGT_OFF);
    int*   bh     = (int*)(ws + BH_OFF);
    int*   bo     = (int*)(ws + BO_OFF);
    char*  wpk    = ws + WPK_OFF;

    hipMemsetAsync(counts, 0, NEXP * sizeof(int), stream);

    wsplit_kernel<<<256, 256, 0, stream>>>(gw, wpk);
    fused_kernel<<<NBLK, 512, 0, stream>>>(x, wpk, wgt, sel, counts, bh);
    scan_kernel<<<NEXP, 512, 0, stream>>>(bh, counts, bo, out);
    scatter_kernel<<<NBLK, 256, 0, stream>>>(sel, wgt, bo, out);
}

// Round 9
// 117.973 us; speedup vs baseline: 2.6962x; 1.0839x over previous
//
#include <hip/hip_runtime.h>
#include <math.h>

typedef _Float16 f16;
typedef f16 f16x8 __attribute__((ext_vector_type(8)));
typedef float f32x4 __attribute__((ext_vector_type(4)));

#define NT    16384
#define DIM   4096
#define NEXP  128
#define TOPK  8
#define NFLAT (NT * TOPK)   // 131072
#define BT    64            // tokens per fused block
#define NFB   (NT / BT)     // 256 fused blocks (1 per CU)
#define SBLK  512           // sort blocks (256 sel entries each)
#define BK    64
#define NSTEP (DIM / BK)    // 64

// ---- workspace layout (bytes) ----
#define COUNTS_OFF 0
#define SEL_OFF    1024
#define WGT_OFF    (SEL_OFF + NFLAT * 4)
#define BH_OFF     (WGT_OFF + NFLAT * 4)
#define BO_OFF     (BH_OFF + NEXP * SBLK * 4)
#define WPK_OFF    (BO_OFF + NEXP * SBLK * 4)   // 2 MB packed W

#define G1P __attribute__((address_space(1)))
#define L3P __attribute__((address_space(3)))

__device__ __forceinline__ void gload_lds16(const void* g, void* l) {
    __builtin_amdgcn_global_load_lds((const G1P unsigned int*)g,
                                     (L3P unsigned int*)l, 16, 0, 0);
}

// fp32 -> fp16 high + scaled residual (next ~11 mantissa bits, normal range)
__device__ __forceinline__ void split2(float v, f16& h, f16& m) {
    h = (f16)v;
    m = (f16)((v - (float)h) * 2048.0f);
}

// ============ prologue: pack 64*gw into fragment-ordered f16 chunks ============
// wpk[(st*8+g)*4096 + c*1024 + lane*16]: c0=h,kk0 c1=h,kk1 c2=m,kk0 c3=m,kk1
__global__ __launch_bounds__(256)
void wsplit_kernel(const float* __restrict__ gw, char* __restrict__ wpk) {
    const int t = blockIdx.x * 256 + threadIdx.x;    // 65536 threads
    const int l = t & 63, kkc = (t >> 6) & 1, g = (t >> 7) & 7, st = t >> 10;
    const int e = g * 16 + (l & 15);
    const int k0 = st * 64 + kkc * 32 + (l >> 4) * 8;
    float4 a = *(const float4*)&gw[e * 4096 + k0];
    float4 b = *(const float4*)&gw[e * 4096 + k0 + 4];
    union { f16 f[8]; uint4 u; } ph, pm;
    split2(a.x * 64.f, ph.f[0], pm.f[0]); split2(a.y * 64.f, ph.f[1], pm.f[1]);
    split2(a.z * 64.f, ph.f[2], pm.f[2]); split2(a.w * 64.f, ph.f[3], pm.f[3]);
    split2(b.x * 64.f, ph.f[4], pm.f[4]); split2(b.y * 64.f, ph.f[5], pm.f[5]);
    split2(b.z * 64.f, ph.f[6], pm.f[6]); split2(b.w * 64.f, ph.f[7], pm.f[7]);
    const size_t base = ((size_t)(st * 8 + g) * 4 + kkc) * 1024 + l * 16;
    *(uint4*)(wpk + base)        = ph.u;
    *(uint4*)(wpk + base + 2048) = pm.u;
}

// ============ fused: scores -> top-8 -> softmax -> sel/wgt/counts/blockhist ============
// 512 thr (8 waves) = 2 tok-groups x 4 exp-groups; wave tile 32 tok x 32 exp.
// LDS 96KB: XH [2][8 fragblk][64 slot]*16B (0..16K), XM (16K..32K),
//           WB [2][8 g][4 c][64 lane]*16B (32K..96K).
// One barrier/step; pre-barrier s_waitcnt lgkmcnt(0) vmcnt(2); W issued
// before X in the prefetch region (order is correctness-critical for vmcnt).
__global__ __launch_bounds__(512, 2)
void fused_kernel(const float* __restrict__ x, const char* __restrict__ wpk,
                  float* __restrict__ wgt, int* __restrict__ sel,
                  int* __restrict__ counts, int* __restrict__ bh) {
    __shared__ __align__(16) char smem[98304];
    char* WB = smem + 32768;

    const int tid  = threadIdx.x;
    const int tok0 = blockIdx.x * BT;
    const int lane = tid & 63, wid = tid >> 6;
    const int r = wid >> 2, eg = wid & 3;       // tok-group, expert-group
    const int fr = lane & 15, hi = lane >> 4;
    // X staging: thread -> (row, 8-float k-chunk) -> one (kk,hi) frag cell
    const int srow = tid >> 3;                  // 0..63
    const int skq  = (tid & 7) * 8;             // 0..56
    const int xi = srow >> 4, xfr = srow & 15;
    const int xkk = skq >> 5, xhi = (skq >> 3) & 3;
    const int xslot = xhi * 16 + xfr;
    const int xwb = ((xi * 2 + xkk) * 64 + (xslot ^ ((xslot >> 4) << 1))) * 16;
    const int lxs = (lane ^ ((lane >> 4) << 1)) * 16;   // swizzled read slot
    const int myg = 2 * eg + r;                 // this wave's W gload chunk

    f32x4 acc0[2][2], acc1[2][2];
#pragma unroll
    for (int i = 0; i < 2; ++i)
#pragma unroll
        for (int j = 0; j < 2; ++j) {
            acc0[i][j] = (f32x4){0.f, 0.f, 0.f, 0.f};
            acc1[i][j] = (f32x4){0.f, 0.f, 0.f, 0.f};
        }

    const size_t xrow = (size_t)(tok0 + srow) * DIM;

#define X_PREF(RA, RB, SI) { \
    RA = *(const float4*)&x[xrow + (size_t)(SI) * BK + skq]; \
    RB = *(const float4*)&x[xrow + (size_t)(SI) * BK + skq + 4]; }
#define W_PREF(SI, B) { \
    const char* wsrc = wpk + ((size_t)(SI) * 8 + myg) * 4096 + lane * 16; \
    char* wdst = WB + (B) * 32768 + myg * 4096; \
    gload_lds16(wsrc,        wdst); \
    gload_lds16(wsrc + 1024, wdst + 1024); \
    gload_lds16(wsrc + 2048, wdst + 2048); \
    gload_lds16(wsrc + 3072, wdst + 3072); }
#define STAGE(CUR, RA, RB) { \
    union { f16 f[8]; f16x8 v; } ph, pm; \
    split2(RA.x, ph.f[0], pm.f[0]); split2(RA.y, ph.f[1], pm.f[1]); \
    split2(RA.z, ph.f[2], pm.f[2]); split2(RA.w, ph.f[3], pm.f[3]); \
    split2(RB.x, ph.f[4], pm.f[4]); split2(RB.y, ph.f[5], pm.f[5]); \
    split2(RB.z, ph.f[6], pm.f[6]); split2(RB.w, ph.f[7], pm.f[7]); \
    *(f16x8*)(smem + (CUR) * 8192 + xwb) = ph.v; \
    *(f16x8*)(smem + 16384 + (CUR) * 8192 + xwb) = pm.v; }
#define COMPUTE(CUR) { \
    _Pragma("unroll") \
    for (int kk = 0; kk < 2; ++kk) { \
        f16x8 ah[2], am[2], bhf[2], bmf[2]; \
        _Pragma("unroll") \
        for (int i = 0; i < 2; ++i) { \
            const int xb = (CUR) * 8192 + ((2 * r + i) * 2 + kk) * 1024 + lxs; \
            ah[i] = *(const f16x8*)(smem + xb); \
            am[i] = *(const f16x8*)(smem + 16384 + xb); \
        } \
        _Pragma("unroll") \
        for (int j = 0; j < 2; ++j) { \
            const int wb = (CUR) * 32768 + (2 * eg + j) * 4096 + kk * 1024 + lane * 16; \
            bhf[j] = *(const f16x8*)(WB + wb); \
            bmf[j] = *(const f16x8*)(WB + wb + 2048); \
        } \
        _Pragma("unroll") \
        for (int i = 0; i < 2; ++i) \
        _Pragma("unroll") \
        for (int j = 0; j < 2; ++j) { \
            acc0[i][j] = __builtin_amdgcn_mfma_f32_16x16x32_f16(ah[i], bhf[j], acc0[i][j], 0, 0, 0); \
            acc1[i][j] = __builtin_amdgcn_mfma_f32_16x16x32_f16(ah[i], bmf[j], acc1[i][j], 0, 0, 0); \
            acc1[i][j] = __builtin_amdgcn_mfma_f32_16x16x32_f16(am[i], bhf[j], acc1[i][j], 0, 0, 0); \
        } \
    } }
// Order invariants: queue entering a step = [X[st](2), W[st](4), X[st+1](2)];
// STAGE's compiler wait retires X[st]; explicit vmcnt(2) retires W[st] keeping
// X[st+1]; post-barrier region issues W[st+1] THEN X[st+2] (sched_barrier).
#define STEP(CUR, RA, RB, PX, PW, SI, VMSTR) { \
    STAGE(CUR, RA, RB); \
    asm volatile("s_waitcnt lgkmcnt(0) vmcnt(" VMSTR ")" ::: "memory"); \
    __builtin_amdgcn_s_barrier(); \
    if (PW) { W_PREF((SI) + 1, (CUR) ^ 1); } \
    __builtin_amdgcn_sched_barrier(0); \
    if (PX) { X_PREF(RA, RB, (SI) + 2); } \
    __builtin_amdgcn_s_setprio(1); \
    COMPUTE(CUR); \
    __builtin_amdgcn_s_setprio(0); }

    // prologue: W[0] FIRST (so STAGE's X[0] wait retires it), then X[0], X[1]
    float4 a0, b0, a1, b1;
    W_PREF(0, 0);
    X_PREF(a0, b0, 0);
    X_PREF(a1, b1, 1);

    for (int st = 0; st < 62; st += 2) {
        STEP(0, a0, b0, 1, 1, st, "2");
        STEP(1, a1, b1, 1, 1, st + 1, "2");
    }
    STEP(0, a0, b0, 0, 1, 62, "2");
    STEP(1, a1, b1, 0, 0, 63, "0");

    __syncthreads();   // full drain; smem reused below

    // ---- scores -> LDS S[64][129] (stride 129: (tid+e)%32 banks, 2-way) ----
    float* S  = (float*)smem;                    // 33024 B
    int*   h2 = (int*)(smem + 34816);            // [2][128]
#pragma unroll
    for (int i = 0; i < 2; ++i)
#pragma unroll
        for (int j = 0; j < 2; ++j)
#pragma unroll
            for (int q = 0; q < 4; ++q) {
                int t = r * 32 + i * 16 + hi * 4 + q;
                int e = eg * 32 + j * 16 + fr;
                S[t * 129 + e] =
                    (acc0[i][j][q] + acc1[i][j][q] * (1.0f / 2048.0f)) * (1.0f / 64.0f);
            }
    if (tid < 256) h2[tid] = 0;
    __syncthreads();

    // ---- top-8 + softmax-over-8: 64 threads, one token each ----
    if (tid < BT) {
        float bs[8]; int bi[8];
#pragma unroll
        for (int q = 0; q < 8; ++q) { bs[q] = -3.0e38f; bi[q] = 0; }
        for (int e = 0; e < NEXP; ++e) {
            float s = S[tid * 129 + e];
            if (s > bs[7]) {
                int pos = 7;
#pragma unroll
                for (int q = 6; q >= 0; q--) pos = (s > bs[q]) ? q : pos;
#pragma unroll
                for (int q = 7; q >= 1; q--) {
                    bool sh = (q > pos);
                    bs[q] = sh ? bs[q - 1] : bs[q];
                    bi[q] = sh ? bi[q - 1] : bi[q];
                }
#pragma unroll
                for (int q = 0; q < 8; q++)
                    if (q == pos) { bs[q] = s; bi[q] = e; }
            }
        }
        float m = bs[0], sum = 0.f, ex[8];
#pragma unroll
        for (int q = 0; q < 8; ++q) { ex[q] = expf(bs[q] - m); sum += ex[q]; }
        float inv = 1.f / fmaxf(sum, 1e-8f);
        const int tok = tok0 + tid;
#pragma unroll
        for (int q = 0; q < 8; ++q) {
            wgt[tok * TOPK + q] = ex[q] * inv;
            sel[tok * TOPK + q] = bi[q];
            atomicAdd(&h2[(tid >> 5) * NEXP + bi[q]], 1);
        }
    }
    __syncthreads();
    if (tid < NEXP) {
        int c0 = h2[tid], c1 = h2[NEXP + tid];
        bh[tid * SBLK + 2 * blockIdx.x]     = c0;
        bh[tid * SBLK + 2 * blockIdx.x + 1] = c1;
        if (c0 + c1) atomicAdd(&counts[tid], c0 + c1);
    }
}

// ============ scan: expert bases + per-expert exclusive block-scan ============
__global__ void scan_kernel(const int* __restrict__ bh, const int* __restrict__ counts,
                            int* __restrict__ bo, float* __restrict__ out) {
    const int e = blockIdx.x, tid = threadIdx.x;   // 128 blocks x 512 thr
    __shared__ int pre[NEXP];
    __shared__ int wsum[8];
    if (tid < NEXP) pre[tid] = counts[tid];
    __syncthreads();
#pragma unroll
    for (int d = 1; d < NEXP; d <<= 1) {
        int o = (tid < NEXP && tid >= d) ? pre[tid - d] : 0;
        __syncthreads();
        if (tid < NEXP) pre[tid] += o;
        __syncthreads();
    }
    const int gb = (e == 0) ? 0 : pre[e - 1];
    if (tid == 0) out[2 * NFLAT + e] = (float)counts[e];

    const int lane = tid & 63, wid = tid >> 6;
    int v = bh[e * SBLK + tid];
    int sc = v;
#pragma unroll
    for (int d = 1; d < 64; d <<= 1) {
        int o = __shfl_up(sc, d);
        sc += (lane >= d) ? o : 0;
    }
    if (lane == 63) wsum[wid] = sc;
    __syncthreads();
    int add = 0;
#pragma unroll
    for (int ww = 0; ww < 8; ww++) add += (ww < wid) ? wsum[ww] : 0;
    bo[e * SBLK + tid] = gb + sc - v + add;
}

// ============ scatter: stable in-block rank via 7 ballots ============
__global__ void scatter_kernel(const int* __restrict__ sel, const float* __restrict__ wgt,
                               const int* __restrict__ bo, float* __restrict__ out) {
    const int tid = threadIdx.x, b = blockIdx.x;
    const int i = b * 256 + tid;
    const int e = sel[i];
    const int lane = tid & 63, wid = tid >> 6;
    unsigned long long m = ~0ull;
#pragma unroll
    for (int bit = 0; bit < 7; bit++) {
        unsigned long long bal = __ballot((e >> bit) & 1);
        m &= ((e >> bit) & 1) ? bal : ~bal;
    }
    unsigned long long lower = (lane == 0) ? 0ull : (~0ull >> (64 - lane));
    int wrank = __popcll(m & lower);

    __shared__ int wh_[4][NEXP];
    ((int*)wh_)[tid] = 0; ((int*)wh_)[tid + 256] = 0;
    __syncthreads();
    if (wrank == 0) wh_[wid][e] = __popcll(m);
    __syncthreads();
    int off = 0;
#pragma unroll
    for (int ww = 0; ww < 4; ww++) off += (ww < wid) ? wh_[ww][e] : 0;

    int pos = bo[e * SBLK + b] + off + wrank;
    out[pos] = wgt[i];
    out[NFLAT + pos] = (float)(i >> 3);
}

extern "C" void kernel_launch(void* const* d_in, const int* in_sizes, int n_in,
                              void* d_out, int out_size, void* d_ws, size_t ws_size,
                              hipStream_t stream) {
    const float* x  = (const float*)d_in[0];
    const float* gw = (const float*)d_in[1];
    float* out = (float*)d_out;
    char*  ws  = (char*)d_ws;

    int*   counts = (int*)(ws + COUNTS_OFF);
    int*   sel    = (int*)(ws + SEL_OFF);
    float* wgt    = (float*)(ws + WGT_OFF);
    int*   bh     = (int*)(ws + BH_OFF);
    int*   bo     = (int*)(ws + BO_OFF);
    char*  wpk    = ws + WPK_OFF;

    hipMemsetAsync(counts, 0, NEXP * sizeof(int), stream);

    wsplit_kernel<<<256, 256, 0, stream>>>(gw, wpk);
    fused_kernel<<<NFB, 512, 0, stream>>>(x, wpk, wgt, sel, counts, bh);
    scan_kernel<<<NEXP, 512, 0, stream>>>(bh, counts, bo, out);
    scatter_kernel<<<SBLK, 256, 0, stream>>>(sel, wgt, bo, out);
}